// Round 7
// baseline (88.599 us; speedup 1.0000x reference)
//
#include <hip/hip_runtime.h>
#include <math.h>

// Problem constants (fixed by setup_inputs): bs=16, Q=300, C=2, P=320
#define BS 16
#define QN 300
#define CN 2
#define PN 320
#define NN (BS * QN)   // 4800 query rows
#define KPRED 53
#define KTGT 54
#define TILE_N 4       // query rows per block (2 packed pairs) -> 1200 blocks

typedef float v2f __attribute__((ext_vector_type(2)));

static __device__ __forceinline__ v2f fma2(v2f a, v2f b, v2f c) {
    return __builtin_elementwise_fma(a, b, c);
}

// R2 structure (measured best) + packed-fp32 row pairs: thread <-> target p
// (320 threads, 5 waves), block handles TILE_N=4 rows as 2 packed pairs.
// Each lane computes rows (na, nb) simultaneously as float2 -> v_pk_add_f32 /
// v_pk_fma_f32 (2x fp32 rate). abs-adds stay scalar (free abs src modifiers;
// VOP3P has no abs). Target features in registers, vis pre-converted.
__global__ __launch_bounds__(PN) void hungarian_cost_kernel(
    const float* __restrict__ pred_logits,  // [N, 2]
    const float* __restrict__ pred_kpts,    // [N, 53]
    const float* __restrict__ tgt_kpts,     // [P, 54]
    const int*   __restrict__ tgt_ids,      // [P]
    float* __restrict__ out)                // [N, P]
{
    const int p  = threadIdx.x;
    const int n0 = blockIdx.x * TILE_N;

    // ---- per-thread target features (registers) ----
    float tx[18], ty[18], vjf[18], w[17];
    {
        const float* t = tgt_kpts + (size_t)p * KTGT;
        #pragma unroll
        for (int j = 0; j < 18; ++j) {
            tx[j] = t[3 * j];
            ty[j] = t[3 * j + 1];
            const float vv = t[3 * j + 2];
            vjf[j] = (vv == 1.0f) ? 1.0f : 0.0f;
            if (j >= 1) w[j - 1] = vv;   // tgt kpts-class vec aliases vis slots
        }
    }
    const int cls = tgt_ids[p];

    #pragma unroll
    for (int h = 0; h < TILE_N / 2; ++h) {
        const int na = n0 + 2 * h;
        const int nb = na + 1;
        const float* ka = pred_kpts + (size_t)na * KPRED;  // wave-uniform
        const float* kb = pred_kpts + (size_t)nb * KPRED;  // wave-uniform

        const v2f k0  = {ka[0], kb[0]};
        const v2f k1  = {ka[1], kb[1]};
        const v2f dx0 = k0 - (v2f){tx[0], tx[0]};
        const v2f dy0 = k1 - (v2f){ty[0], ty[0]};

        v2f cd = {0.0f, 0.0f};   // cost_deltas
        v2f ck = {0.0f, 0.0f};   // cost_kpts: xa - txa = 2*dx + dx0
        v2f cq = {0.0f, 0.0f};   // kpts-class squared L2
        #pragma unroll
        for (int j = 1; j < 18; ++j) {
            const v2f kx = {ka[3 * j - 1], kb[3 * j - 1]};
            const v2f ky = {ka[3 * j],     kb[3 * j]};
            const v2f kc = {ka[3 * j + 1], kb[3 * j + 1]};
            const v2f vj2 = {vjf[j], vjf[j]};

            const v2f dx = kx - (v2f){tx[j], tx[j]};     // v_pk_add
            const v2f dy = ky - (v2f){ty[j], ty[j]};     // v_pk_add
            const v2f adxy = {fabsf(dx.x) + fabsf(dy.x),  // scalar adds,
                              fabsf(dx.y) + fabsf(dy.y)}; // abs = src mod
            cd = fma2(vj2, adxy, cd);                    // v_pk_fma

            const v2f ax = fma2((v2f){2.0f, 2.0f}, dx, dx0);  // v_pk_fma
            const v2f ay = fma2((v2f){2.0f, 2.0f}, dy, dy0);  // v_pk_fma
            const v2f aaxy = {fabsf(ax.x) + fabsf(ay.x),
                              fabsf(ax.y) + fabsf(ay.y)};
            ck = fma2(vj2, aaxy, ck);                    // v_pk_fma

            const v2f d = kc - (v2f){w[j - 1], w[j - 1]};     // v_pk_add
            cq = fma2(d, d, cq);                         // v_pk_fma
        }

        // ---- per-row epilogues ----
        #pragma unroll
        for (int r = 0; r < 2; ++r) {
            const int n = (r == 0) ? na : nb;
            const float dx0r = (r == 0) ? dx0.x : dx0.y;
            const float dy0r = (r == 0) ? dy0.x : dy0.y;
            const float cdr  = (r == 0) ? cd.x  : cd.y;
            const float ckr  = (r == 0) ? ck.x  : ck.y;
            const float cqr  = (r == 0) ? cq.x  : cq.y;

            const float cc = vjf[0] * sqrtf(fmaf(dx0r, dx0r, dy0r * dy0r));

            const float l0 = pred_logits[n * CN + 0];   // wave-uniform
            const float l1 = pred_logits[n * CN + 1];
            const float m  = fmaxf(l0, l1);
            const float e0 = __expf(l0 - m);
            const float e1 = __expf(l1 - m);
            const float ccls = -((cls == 0) ? e0 : e1) / (e0 + e1);

            out[(size_t)n * PN + p] = ckr + cc + cdr + ccls + sqrtf(cqr);
        }
    }
}

extern "C" void kernel_launch(void* const* d_in, const int* in_sizes, int n_in,
                              void* d_out, int out_size, void* d_ws, size_t ws_size,
                              hipStream_t stream) {
    const float* pred_logits = (const float*)d_in[0];
    const float* pred_kpts   = (const float*)d_in[1];
    const float* tgt_kpts    = (const float*)d_in[2];
    const int*   tgt_ids     = (const int*)d_in[3];
    float* out = (float*)d_out;

    hipLaunchKernelGGL(hungarian_cost_kernel, dim3(NN / TILE_N), dim3(PN), 0, stream,
                       pred_logits, pred_kpts, tgt_kpts, tgt_ids, out);
}